// Round 9
// baseline (1769.082 us; speedup 1.0000x reference)
//
#include <hip/hip_runtime.h>
#include <stdint.h>

#define ALPHA 0.1f
#define NN 20000
#define DF 768
#define NE 200000
#define NB 64
#define TSEQ 128
#define SF 128
#define HS 512
#define NCLS 14

typedef __attribute__((ext_vector_type(8))) short short8;
typedef __attribute__((ext_vector_type(4))) float f32x4;
typedef __attribute__((ext_vector_type(4))) unsigned int u32x4;

// ---------------- workspace layout (bytes) ----------------
#define OFF_DEG     0u           // int[20000]
#define OFF_CSRC    80000u       // int[20000]
#define OFF_CNTB    160000u      // int[64]
#define OFF_FLAG64  176640u      // int[1] : 1 if indices are int64
#define ZERO_INTS   44161u       // zero [0, 176644)
#define OFF_ROWPTR  176896u      // int[20001]
#define OFF_CURSOR  257024u      // int[20000]
#define OFF_DINV    337024u      // float[20000]
#define OFF_COL     417024u      // int[200000]
#define OFF_WGT     1217024u     // float[200000]
#define OFF_V0      2017280u     // fp16[20000*64] (2.56 MB — fits per-XCD L2)
#define OFF_V1      7137280u     // fp16[20000*64]
#define OFF_HBUF    12257280u    // u32 [2][2][64][256]  (2 x bf16 h, untagged)
#define OFF_HFLAG   12519424u    // u32 [2][2][8][64]    (rank flags = step tag)
#define OFF_YSEQ    12781568u    // float[64*1024]
#define OFF_PART    13240320u    // float[16][64][768]

__device__ __forceinline__ unsigned short f2b(float f) {
  union { float f; unsigned u; } v; v.f = f;
  unsigned u = v.u;
  return (unsigned short)((u + 0x7FFFu + ((u >> 16) & 1u)) >> 16);
}

union U16h { unsigned short u; _Float16 h; };
__device__ __forceinline__ float h2f(unsigned short u) {
  U16h t; t.u = u; return (float)t.h;
}
__device__ __forceinline__ unsigned short f2h(float f) {
  U16h t; t.h = (_Float16)f; return t.u;
}

__device__ __forceinline__ int idx_at(const int* p, long long i, int mode64) {
  return mode64 ? p[2*i] : p[i];   // little-endian low word
}

__device__ __forceinline__ float dot4(float4 a, float4 b) {
  return a.x * b.x + a.y * b.y + a.z * b.z + a.w * b.w;
}

// ---------------- small utility kernels ----------------
__global__ void zero2_kernel(int* p1, int n1, int* p2, int n2) {
  int i = blockIdx.x * blockDim.x + threadIdx.x;
  if (i < n1) p1[i] = 0;
  int j = i - n1;
  if (j >= 0 && j < n2) p2[j] = 0;
}

// 64-lane parallel i64 detection
__global__ void detect_i64_kernel(const int* e, int* flag) {
  int lane = threadIdx.x;
  int ok = 1;
  for (int i = lane; i < 256; i += 64) ok &= (e[2 * i + 1] == 0);
  ok = __all(ok);
  if (lane == 0 && blockIdx.x == 0) *flag = ok ? 1 : 0;
}

// atomics only on 20000-entry arrays (no few-address hotspots — R6 lesson)
__global__ void hist_kernel(const int* e, const int* batch, int* deg, int* csrc,
                            int* cntb, const int* flag) {
  int i = blockIdx.x * blockDim.x + threadIdx.x;
  int m = *flag;
  if (i < NE) {
    int s = idx_at(e, i, m);
    int d = idx_at(e, (long long)NE + i, m);
    atomicAdd(&csrc[s], 1);
    atomicAdd(&deg[d], 1);
  }
  if (i < NN) atomicAdd(&cntb[idx_at(batch, i, m)], 1);
}

// blocks 0-19: exclusive scan of csrc chunk b; carry by grid-stride sum of
// csrc[0..b*1000) (no atomics). Also dinv. blocks 20+: v0init fp16.
__global__ __launch_bounds__(1024) void combo_kernel(
    const int* __restrict__ csrc, const int* __restrict__ deg,
    int* __restrict__ row_ptr, int* __restrict__ cursor,
    float* __restrict__ dinv, const int* __restrict__ batch,
    const int* __restrict__ flag, unsigned short* __restrict__ v0) {
  const int tid = threadIdx.x, b = blockIdx.x;
  if (b < 20) {
    __shared__ int sA[1024], sB[1024];
    __shared__ int wred[16];
    __shared__ int carry_s;
    int psum = 0;
    for (int i = tid; i < b * 1000; i += 1024) psum += csrc[i];
    for (int off = 1; off < 64; off <<= 1) psum += __shfl_xor(psum, off);
    if ((tid & 63) == 0) wred[tid >> 6] = psum;
    __syncthreads();
    if (tid == 0) {
      int c = 0;
#pragma unroll
      for (int w = 0; w < 16; ++w) c += wred[w];
      carry_s = c;
    }
    int i = b * 1000 + tid;
    int active = (tid < 1000);
    int v = active ? csrc[i] : 0;
    sA[tid] = v;
    __syncthreads();
    int carry = carry_s;
    int* src = sA; int* dst = sB;
    for (int off = 1; off < 1024; off <<= 1) {
      dst[tid] = src[tid] + (tid >= off ? src[tid - off] : 0);
      __syncthreads();
      int* t = src; src = dst; dst = t;
    }
    if (active) {
      int ex = carry + src[tid] - v;
      row_ptr[i] = ex; cursor[i] = ex;
      dinv[i] = rsqrtf((float)(deg[i] + 1));   // +1 self loop
    }
    if (b == 19 && tid == 0) row_ptr[NN] = carry + src[999];
  } else {
    int m = *flag;
    long long j = (long long)(b - 20) * 1024 + tid;
    if (j < (long long)NN * 64) {
      int n = (int)(j >> 6), gb = (int)(j & 63);
      v0[j] = (idx_at(batch, n, m) == gb) ? (unsigned short)0x3C00 : 0;  // fp16 1.0
    }
  }
}

__global__ void fill_kernel(const int* e, const float* dinv, int* cursor,
                            int* colA, float* wgt, const int* flag) {
  int i = blockIdx.x * blockDim.x + threadIdx.x;
  if (i >= NE) return;
  int m = *flag;
  int s = idx_at(e, i, m);
  int d = idx_at(e, (long long)NE + i, m);
  int pos = atomicAdd(&cursor[s], 1);
  colA[pos] = d;
  wgt[pos] = dinv[s] * dinv[d];
}

// one wave per node; 16-edge ILP; V in fp16 (128 B rows — 2x less traffic and
// whole V fits per-XCD L2). Math in f32; round only on the row store.
__global__ __launch_bounds__(256) void hop_kernel(
    const unsigned short* __restrict__ vin, unsigned short* __restrict__ vout,
    const int* __restrict__ row_ptr, const int* __restrict__ colA,
    const float* __restrict__ wgt, const float* __restrict__ dinv,
    const int* __restrict__ batch, const int* __restrict__ flag) {
  int wid = (blockIdx.x * blockDim.x + threadIdx.x) >> 6;
  int lane = threadIdx.x & 63;
  if (wid >= NN) return;
  const int quad = lane >> 4, l15 = lane & 15;
  const int c4 = l15 * 4;
  float di = dinv[wid];
  int e0 = __builtin_amdgcn_readfirstlane(row_ptr[wid]);
  int e1 = __builtin_amdgcn_readfirstlane(row_ptr[wid + 1]);

  float ax, ay, az, aw;
  {
    float w = (quad == 0) ? di * di : 0.0f;
    ushort4 sv = *(const ushort4*)(vin + (size_t)wid * 64 + c4);
    ax = w * h2f(sv.x); ay = w * h2f(sv.y); az = w * h2f(sv.z); aw = w * h2f(sv.w);
  }
  for (int e = e0; e < e1; e += 16) {
    int i0 = e + quad, i1 = i0 + 4, i2 = i0 + 8, i3 = i0 + 12;
    int a0 = (i0 < e1), a1 = (i1 < e1), a2 = (i2 < e1), a3 = (i3 < e1);
    int j0 = a0 ? i0 : e0, j1 = a1 ? i1 : e0, j2 = a2 ? i2 : e0, j3 = a3 ? i3 : e0;
    int cc0 = colA[j0], cc1 = colA[j1], cc2 = colA[j2], cc3 = colA[j3];
    float w0 = a0 ? wgt[j0] : 0.0f, w1 = a1 ? wgt[j1] : 0.0f;
    float w2 = a2 ? wgt[j2] : 0.0f, w3 = a3 ? wgt[j3] : 0.0f;
    ushort4 v0 = *(const ushort4*)(vin + (size_t)cc0 * 64 + c4);
    ushort4 v1 = *(const ushort4*)(vin + (size_t)cc1 * 64 + c4);
    ushort4 v2 = *(const ushort4*)(vin + (size_t)cc2 * 64 + c4);
    ushort4 v3 = *(const ushort4*)(vin + (size_t)cc3 * 64 + c4);
    ax += w0 * h2f(v0.x) + w1 * h2f(v1.x) + w2 * h2f(v2.x) + w3 * h2f(v3.x);
    ay += w0 * h2f(v0.y) + w1 * h2f(v1.y) + w2 * h2f(v2.y) + w3 * h2f(v3.y);
    az += w0 * h2f(v0.z) + w1 * h2f(v1.z) + w2 * h2f(v2.z) + w3 * h2f(v3.z);
    aw += w0 * h2f(v0.w) + w1 * h2f(v1.w) + w2 * h2f(v2.w) + w3 * h2f(v3.w);
  }
  ax += __shfl_xor(ax, 16); ax += __shfl_xor(ax, 32);
  ay += __shfl_xor(ay, 16); ay += __shfl_xor(ay, 32);
  az += __shfl_xor(az, 16); az += __shfl_xor(az, 32);
  aw += __shfl_xor(aw, 16); aw += __shfl_xor(aw, 32);
  if (quad == 0) {
    int b = idx_at(batch, wid, *flag);
    ushort4 r;
    r.x = f2h((1.0f - ALPHA) * ax + ((b == c4 + 0) ? ALPHA : 0.0f));
    r.y = f2h((1.0f - ALPHA) * ay + ((b == c4 + 1) ? ALPHA : 0.0f));
    r.z = f2h((1.0f - ALPHA) * az + ((b == c4 + 2) ? ALPHA : 0.0f));
    r.w = f2h((1.0f - ALPHA) * aw + ((b == c4 + 3) ? ALPHA : 0.0f));
    *(ushort4*)(vout + (size_t)wid * 64 + c4) = r;
  }
}

// ---------------- fused GRU + spmm (block-role union) ------------------------
// blocks 0-511: gru (R3-proven flag-exchange; only wave 0 active, waves 1-3
// exit). blocks 512-1279: spmm (pooled partials, 4 waves). The gru is ~95%
// stalled on exchange waits at 2 waves/CU — spmm's ~40 us of bandwidth work
// runs inside those stalls for free. gru blocks dispatched first; spmm blocks
// retire independently (no cross-role deps; poll guard >> any transient).
#define SMEM_BYTES 17408   // max(gru hl 10368, spmm red 4*64*17*4)

__global__ __launch_bounds__(256) void gru_spmm_kernel(
    const float* __restrict__ seq,
    const float* __restrict__ wih_f, const float* __restrict__ whh_f,
    const float* __restrict__ bih_f, const float* __restrict__ bhh_f,
    const float* __restrict__ wih_b, const float* __restrict__ whh_b,
    const float* __restrict__ bih_b, const float* __restrict__ bhh_b,
    unsigned* __restrict__ hbuf, unsigned* __restrict__ hflag,
    float* __restrict__ y_seq,
    const unsigned short* __restrict__ S, const float* __restrict__ x,
    float* __restrict__ partial) {
  __shared__ char smem[SMEM_BYTES];

  if (blockIdx.x >= 512) {
    // ================= spmm role =================
    float (*red)[64][17] = (float(*)[64][17])smem;
    int tid = threadIdx.x;
    int w = tid >> 6, lane = tid & 63;
    int beta = blockIdx.x - 512;
    int ft = beta % 48, cg = beta / 48;
    int ch = cg * 4 + w;
    int f0 = ft * 16;
    int n0 = (ch * NN) >> 6, n1 = ((ch + 1) * NN) >> 6;
    float acc[16];
#pragma unroll
    for (int f = 0; f < 16; ++f) acc[f] = 0.0f;
    for (int n = n0; n < n1; ++n) {
      float sv = h2f(S[n * 64 + lane]);
      const float4* xr = (const float4*)(x + (size_t)n * DF + f0);
      float4 x0 = xr[0], x1 = xr[1], x2 = xr[2], x3 = xr[3];
      acc[0] += sv * x0.x; acc[1] += sv * x0.y; acc[2] += sv * x0.z; acc[3] += sv * x0.w;
      acc[4] += sv * x1.x; acc[5] += sv * x1.y; acc[6] += sv * x1.z; acc[7] += sv * x1.w;
      acc[8] += sv * x2.x; acc[9] += sv * x2.y; acc[10] += sv * x2.z; acc[11] += sv * x2.w;
      acc[12] += sv * x3.x; acc[13] += sv * x3.y; acc[14] += sv * x3.z; acc[15] += sv * x3.w;
    }
#pragma unroll
    for (int f = 0; f < 16; ++f) red[w][lane][f] = acc[f];
    __syncthreads();
#pragma unroll
    for (int ff = 0; ff < 4; ++ff) {
      int f = w * 4 + ff;
      float s = red[0][lane][f] + red[1][lane][f] + red[2][lane][f] + red[3][lane][f];
      partial[((size_t)(cg * 64 + lane)) * DF + f0 + f] = s;
    }
    return;
  }

  // ================= gru role (wave 0 only) =================
  if (threadIdx.x >= 64) return;
  unsigned short* hl = (unsigned short*)smem;   // [8][648]

  const int lane = threadIdx.x;
  const int quad = lane >> 4, l15 = lane & 15;
  const int d  = blockIdx.x >> 8;         // 0 fwd, 1 bwd
  const int g  = (blockIdx.x >> 5) & 7;   // 8 groups
  const int rk = blockIdx.x & 31;         // 32 ranks
  const int seqbase = g * 8;
  const int c0 = rk * 16;

  const float* WHHd = d ? whh_b : whh_f;
  const float* WIHd = d ? wih_b : wih_f;
  const float* BIHd = d ? bih_b : bih_f;
  const float* BHHd = d ? bhh_b : bhh_f;

  auto ldw = [&](int gcol, int j) -> short8 {
    int k0 = j * 32 + quad * 8;
    const float* p = (k0 < 512) ? (WHHd + (size_t)gcol * 512 + k0)
                                : (WIHd + (size_t)gcol * 128 + (k0 - 512));
    float4 f0 = *(const float4*)p;
    float4 f1 = *(const float4*)(p + 4);
    short8 r;
    r[0] = (short)f2b(f0.x); r[1] = (short)f2b(f0.y);
    r[2] = (short)f2b(f0.z); r[3] = (short)f2b(f0.w);
    r[4] = (short)f2b(f1.x); r[5] = (short)f2b(f1.y);
    r[6] = (short)f2b(f1.z); r[7] = (short)f2b(f1.w);
    return r;
  };
  short8 wr[20], wz[20], wn[20];
#pragma unroll
  for (int j = 0; j < 20; ++j) {
    wr[j] = ldw(c0 + l15, j);
    wz[j] = ldw(512 + c0 + l15, j);
    wn[j] = ldw(1024 + c0 + l15, j);
  }

  auto stage_x = [&](int t_x) {
    int tt = d ? (127 - t_x) : t_x;
    int s = lane >> 3, k0 = (lane & 7) * 16;
    const float* sp = seq + (size_t)(seqbase + s) * (TSEQ * SF) + tt * SF + k0;
    float4 a = *(const float4*)sp;
    float4 b = *(const float4*)(sp + 4);
    float4 c = *(const float4*)(sp + 8);
    float4 e = *(const float4*)(sp + 12);
    unsigned* xq = (unsigned*)(hl + s * 648 + 512 + k0);   // 16B aligned
    xq[0] = (unsigned)f2b(a.x) | ((unsigned)f2b(a.y) << 16);
    xq[1] = (unsigned)f2b(a.z) | ((unsigned)f2b(a.w) << 16);
    xq[2] = (unsigned)f2b(b.x) | ((unsigned)f2b(b.y) << 16);
    xq[3] = (unsigned)f2b(b.z) | ((unsigned)f2b(b.w) << 16);
    xq[4] = (unsigned)f2b(c.x) | ((unsigned)f2b(c.y) << 16);
    xq[5] = (unsigned)f2b(c.z) | ((unsigned)f2b(c.w) << 16);
    xq[6] = (unsigned)f2b(e.x) | ((unsigned)f2b(e.y) << 16);
    xq[7] = (unsigned)f2b(e.z) | ((unsigned)f2b(e.w) << 16);
  };

  for (int i = lane; i < 8 * 512; i += 64)
    hl[(i >> 9) * 648 + (i & 511)] = 0;
  stage_x(0);

  const float b_r  = BIHd[c0 + l15] + BHHd[c0 + l15];
  const float b_z  = BIHd[512 + c0 + l15] + BHHd[512 + c0 + l15];
  const float b_in = BIHd[1024 + c0 + l15];
  const float b_hn = BHHd[1024 + c0 + l15];

  float hprev[4] = {0, 0, 0, 0};
  float msum[4]  = {0, 0, 0, 0};
  float mxv[4]   = {-1e30f, -1e30f, -1e30f, -1e30f};

  for (int t = 0; t < 128; ++t) {
    f32x4 ar = {0, 0, 0, 0}, az = {0, 0, 0, 0};
    f32x4 anh = {0, 0, 0, 0}, anx = {0, 0, 0, 0};
    const unsigned short* arow = hl + (l15 & 7) * 648 + quad * 8;
#pragma unroll
    for (int kc = 0; kc < 20; ++kc) {
      short8 af = *(const short8*)(arow + kc * 32);
      ar = __builtin_amdgcn_mfma_f32_16x16x32_bf16(af, wr[kc], ar, 0, 0, 0);
      az = __builtin_amdgcn_mfma_f32_16x16x32_bf16(af, wz[kc], az, 0, 0, 0);
      if (kc < 16)
        anh = __builtin_amdgcn_mfma_f32_16x16x32_bf16(af, wn[kc], anh, 0, 0, 0);
      else
        anx = __builtin_amdgcn_mfma_f32_16x16x32_bf16(af, wn[kc], anx, 0, 0, 0);
    }

    float h2v[4];
#pragma unroll
    for (int rr = 0; rr < 4; ++rr) {
      float r = 1.0f / (1.0f + __expf(-(ar[rr] + b_r)));
      float z = 1.0f / (1.0f + __expf(-(az[rr] + b_z)));
      float narg = anx[rr] + b_in + r * (anh[rr] + b_hn);
      float e2 = __expf(-2.0f * fabsf(narg));
      float nt = (1.0f - e2) / (1.0f + e2);
      nt = (narg < 0.0f) ? -nt : nt;
      float h2 = (1.0f - z) * nt + z * hprev[rr];
      hprev[rr] = h2; msum[rr] += h2; mxv[rr] = fmaxf(mxv[rr], h2);
      h2v[rr] = h2;
    }

    if (t < 127) {
      const int slot = (t + 1) & 1;
      const unsigned tag = (unsigned)(t + 1);
#pragma unroll
      for (int rr = 0; rr < 4; ++rr) {
        unsigned me = f2b(h2v[rr]);
        unsigned nb = (unsigned)__shfl_xor((int)me, 1);
        if (lane < 32 && !(lane & 1)) {
          int row = (lane >> 4) * 4 + rr;
          unsigned word = (me & 0xFFFFu) | (nb << 16);
          unsigned* dp = hbuf +
              ((size_t)((slot * 2 + d) * 64 + seqbase + row)) * 256 +
              (unsigned)((c0 + (lane & 15)) >> 1);
          asm volatile("global_store_dword %0, %1, off sc0 sc1"
                       :: "v"(dp), "v"(word) : "memory");
        }
      }
      asm volatile("s_waitcnt vmcnt(0)" ::: "memory");   // release: data ack'd
      if (lane == 0) {
        unsigned* fpo = hflag + ((size_t)(slot * 2 + d) * 8 + g) * 64 + rk;
        unsigned tv = tag;
        asm volatile("global_store_dword %0, %1, off sc0 sc1"
                     :: "v"(fpo), "v"(tv) : "memory");
      }
      stage_x(t + 1);
      const unsigned* fp = hflag + ((size_t)(slot * 2 + d) * 8 + g) * 64 + (lane & 31);
      int guard = 0;
      unsigned fv;
      for (;;) {
        asm volatile("global_load_dword %0, %1, off sc0 sc1"
                     : "=v"(fv) : "v"(fp) : "memory");
        asm volatile("s_waitcnt vmcnt(0)" ::: "memory");
        __builtin_amdgcn_sched_barrier(0);
        if (__all(fv == tag)) break;
        if (++guard > (1 << 20)) break;
        __builtin_amdgcn_s_sleep(1);
      }
      const unsigned* db = hbuf + (size_t)((slot * 2 + d) * 64 + seqbase) * 256;
      u32x4 w[8];
#pragma unroll
      for (int c = 0; c < 8; ++c)
        asm volatile("global_load_dwordx4 %0, %1, off sc0 sc1"
                     : "=v"(w[c]) : "v"(db + c * 256 + lane * 4) : "memory");
      asm volatile("s_waitcnt vmcnt(0)" ::: "memory");
      __builtin_amdgcn_sched_barrier(0);
#pragma unroll
      for (int c = 0; c < 8; ++c) {
        unsigned* dp = (unsigned*)(hl + c * 648) + lane * 4;
        dp[0] = w[c][0]; dp[1] = w[c][1]; dp[2] = w[c][2]; dp[3] = w[c][3];
      }
    }
  }

  if (lane < 32) {
#pragma unroll
    for (int rr = 0; rr < 4; ++rr) {
      int row = (lane >> 4) * 4 + rr;
      y_seq[(size_t)(seqbase + row) * 1024 + d * 512 + c0 + l15] =
          msum[rr] * (1.0f / 128.0f) + mxv[rr];
    }
  }
}

// fused seq MLP: 1024 -> 512 -> 256 -> 14, one block per batch row
__global__ __launch_bounds__(256) void mlp_seq_kernel(
    const float* __restrict__ y_seq,
    const float* __restrict__ w0, const float* __restrict__ b0,
    const float* __restrict__ w1, const float* __restrict__ b1,
    const float* __restrict__ w2, const float* __restrict__ b2,
    float* __restrict__ out) {
  __shared__ float a0[1024], h1[512], h2[256];
  const int tid = threadIdx.x, b = blockIdx.x;
  ((float4*)a0)[tid] = ((const float4*)(y_seq + (size_t)b * 1024))[tid];
  __syncthreads();
  {
    int n = tid * 2;
    float acc0 = b0[n], acc1 = b0[n + 1];
    const float4* wa = (const float4*)(w0 + (size_t)n * 1024);
    const float4* wb = wa + 256;
#pragma unroll 4
    for (int k = 0; k < 256; ++k) {
      float4 av = ((float4*)a0)[k];
      acc0 += dot4(av, wa[k]);
      acc1 += dot4(av, wb[k]);
    }
    h1[n] = fmaxf(acc0, 0.0f);
    h1[n + 1] = fmaxf(acc1, 0.0f);
  }
  __syncthreads();
  {
    float acc = b1[tid];
    const float4* wa = (const float4*)(w1 + (size_t)tid * 512);
#pragma unroll 4
    for (int k = 0; k < 128; ++k) acc += dot4(((float4*)h1)[k], wa[k]);
    h2[tid] = fmaxf(acc, 0.0f);
  }
  __syncthreads();
  if (tid < 224) {
    int o = tid >> 4, l = tid & 15;
    const float4* wa = (const float4*)(w2 + (size_t)o * 256);
    float part = 0.0f;
#pragma unroll
    for (int k = l; k < 64; k += 16) part += dot4(((float4*)h2)[k], wa[k]);
    part += __shfl_xor(part, 1); part += __shfl_xor(part, 2);
    part += __shfl_xor(part, 4); part += __shfl_xor(part, 8);
    if (l == 0) out[b * NCLS + o] = part + b2[o];
  }
}

// fused graph MLP: (16-slab reduce + /cnt) -> 768 -> 384 -> 192 -> 14
__global__ __launch_bounds__(256) void mlp_graph_kernel(
    const float* __restrict__ partial, const int* __restrict__ cntb,
    const float* __restrict__ w0, const float* __restrict__ b0,
    const float* __restrict__ w1, const float* __restrict__ b1,
    const float* __restrict__ w2, const float* __restrict__ b2,
    float* __restrict__ out) {
  __shared__ float a0[768], h1[384], h2[192];
  const int tid = threadIdx.x, b = blockIdx.x;
  int cnt = cntb[b]; if (cnt < 1) cnt = 1;
  const float cinv = 1.0f / (float)cnt;
  if (tid < 192) {
    float4 s = {0, 0, 0, 0};
#pragma unroll
    for (int c = 0; c < 16; ++c) {
      float4 p = ((const float4*)(partial + ((size_t)(c * 64 + b)) * DF))[tid];
      s.x += p.x; s.y += p.y; s.z += p.z; s.w += p.w;
    }
    s.x *= cinv; s.y *= cinv; s.z *= cinv; s.w *= cinv;
    ((float4*)a0)[tid] = s;
  }
  __syncthreads();
  if (tid < 192) {
    int n = tid * 2;
    float acc0 = b0[n], acc1 = b0[n + 1];
    const float4* wa = (const float4*)(w0 + (size_t)n * 768);
    const float4* wb = wa + 192;
#pragma unroll 4
    for (int k = 0; k < 192; ++k) {
      float4 av = ((float4*)a0)[k];
      acc0 += dot4(av, wa[k]);
      acc1 += dot4(av, wb[k]);
    }
    h1[n] = fmaxf(acc0, 0.0f);
    h1[n + 1] = fmaxf(acc1, 0.0f);
  }
  __syncthreads();
  if (tid < 192) {
    float acc = b1[tid];
    const float4* wa = (const float4*)(w1 + (size_t)tid * 384);
#pragma unroll 4
    for (int k = 0; k < 96; ++k) acc += dot4(((float4*)h1)[k], wa[k]);
    h2[tid] = fmaxf(acc, 0.0f);
  }
  __syncthreads();
  if (tid < 224) {
    int o = tid >> 4, l = tid & 15;
    const float4* wa = (const float4*)(w2 + (size_t)o * 192);
    float part = 0.0f;
#pragma unroll
    for (int k = l; k < 48; k += 16) part += dot4(((float4*)h2)[k], wa[k]);
    part += __shfl_xor(part, 1); part += __shfl_xor(part, 2);
    part += __shfl_xor(part, 4); part += __shfl_xor(part, 8);
    if (l == 0) atomicAdd(&out[b * NCLS + o], part + b2[o]);
  }
}

// ---------------- launcher ----------------
extern "C" void kernel_launch(void* const* d_in, const int* in_sizes, int n_in,
                              void* d_out, int out_size, void* d_ws, size_t ws_size,
                              hipStream_t stream) {
  const float* x      = (const float*)d_in[0];
  const int*   eidx   = (const int*)d_in[1];
  const float* seq    = (const float*)d_in[2];
  const int*   batch  = (const int*)d_in[3];
  const float* wih_f  = (const float*)d_in[4];
  const float* whh_f  = (const float*)d_in[5];
  const float* bih_f  = (const float*)d_in[6];
  const float* bhh_f  = (const float*)d_in[7];
  const float* wih_b  = (const float*)d_in[8];
  const float* whh_b  = (const float*)d_in[9];
  const float* bih_b  = (const float*)d_in[10];
  const float* bhh_b  = (const float*)d_in[11];
  const float* mg_w0  = (const float*)d_in[12];
  const float* mg_b0  = (const float*)d_in[13];
  const float* mg_w1  = (const float*)d_in[14];
  const float* mg_b1  = (const float*)d_in[15];
  const float* mg_w2  = (const float*)d_in[16];
  const float* mg_b2  = (const float*)d_in[17];
  const float* ms_w0  = (const float*)d_in[18];
  const float* ms_b0  = (const float*)d_in[19];
  const float* ms_w1  = (const float*)d_in[20];
  const float* ms_b1  = (const float*)d_in[21];
  const float* ms_w2  = (const float*)d_in[22];
  const float* ms_b2  = (const float*)d_in[23];
  float* out = (float*)d_out;
  char* ws = (char*)d_ws;

  int*   deg     = (int*)(ws + OFF_DEG);
  int*   csrc    = (int*)(ws + OFF_CSRC);
  int*   cntb    = (int*)(ws + OFF_CNTB);
  int*   flag    = (int*)(ws + OFF_FLAG64);
  int*   row_ptr = (int*)(ws + OFF_ROWPTR);
  int*   cursor  = (int*)(ws + OFF_CURSOR);
  float* dinv    = (float*)(ws + OFF_DINV);
  int*   colA    = (int*)(ws + OFF_COL);
  float* wgtA    = (float*)(ws + OFF_WGT);
  unsigned short* V0 = (unsigned short*)(ws + OFF_V0);
  unsigned short* V1 = (unsigned short*)(ws + OFF_V1);
  unsigned* hbuf = (unsigned*)(ws + OFF_HBUF);
  unsigned* hflag= (unsigned*)(ws + OFF_HFLAG);
  float* y_seq   = (float*)(ws + OFF_YSEQ);
  float* part    = (float*)(ws + OFF_PART);

  // ---- graph prep ----
  zero2_kernel<<<(ZERO_INTS + 2048 + 255) / 256, 256, 0, stream>>>(
      (int*)ws, (int)ZERO_INTS, (int*)(ws + OFF_HFLAG), 2048);
  detect_i64_kernel<<<1, 64, 0, stream>>>(eidx, flag);
  hist_kernel<<<(NE + 255) / 256, 256, 0, stream>>>(eidx, batch, deg, csrc,
                                                    cntb, flag);
  combo_kernel<<<20 + (NN * 64 + 1023) / 1024, 1024, 0, stream>>>(
      csrc, deg, row_ptr, cursor, dinv, batch, flag, V0);
  fill_kernel<<<(NE + 255) / 256, 256, 0, stream>>>(eidx, dinv, cursor, colA, wgtA, flag);

  // ---- APPNP: 16 hop dispatches (fp16 V, 16-edge ILP) ----
  for (int h = 0; h < 16; ++h) {
    const unsigned short* vin = (h & 1) ? V1 : V0;
    unsigned short* vout = (h & 1) ? V0 : V1;
    hop_kernel<<<(NN * 64 + 255) / 256, 256, 0, stream>>>(vin, vout, row_ptr, colA,
                                                          wgtA, dinv, batch, flag);
  }

  // ---- fused BiGRU + spmm (spmm hides in gru's exchange stalls) ----
  gru_spmm_kernel<<<512 + 768, 256, 0, stream>>>(
      seq, wih_f, whh_f, bih_f, bhh_f, wih_b, whh_b, bih_b, bhh_b,
      hbuf, hflag, y_seq, V0, x, part);

  // ---- fused MLPs: seq writes out, graph accumulates ----
  mlp_seq_kernel<<<64, 256, 0, stream>>>(y_seq, ms_w0, ms_b0, ms_w1, ms_b1,
                                         ms_w2, ms_b2, out);
  mlp_graph_kernel<<<64, 256, 0, stream>>>(part, cntb, mg_w0, mg_b0, mg_w1, mg_b1,
                                           mg_w2, mg_b2, out);
  (void)in_sizes; (void)n_in; (void)out_size; (void)ws_size;
}

// Round 10
// 1224.490 us; speedup vs baseline: 1.4448x; 1.4448x over previous
//
#include <hip/hip_runtime.h>
#include <stdint.h>

#define ALPHA 0.1f
#define NN 20000
#define DF 768
#define NE 200000
#define NB 64
#define TSEQ 128
#define SF 128
#define HS 512
#define NCLS 14

typedef __attribute__((ext_vector_type(8))) short short8;
typedef __attribute__((ext_vector_type(4))) float f32x4;
typedef __attribute__((ext_vector_type(4))) unsigned int u32x4;

// ---------------- workspace layout (bytes) ----------------
#define OFF_DEG     0u           // int[20000]
#define OFF_CSRC    80000u       // int[20000]
#define OFF_CNTB    160000u      // int[64]
#define OFF_FLAG64  176640u      // int[1] : 1 if indices are int64
#define ZERO_INTS   44161u       // zero [0, 176644)
#define OFF_ROWPTR  176896u      // int[20001]
#define OFF_CURSOR  257024u      // int[20000]
#define OFF_DINV    337024u      // float[20000]
#define OFF_COL     417024u      // int[200000]
#define OFF_WGT     1217024u     // float[200000]
#define OFF_V0      2017280u     // fp16[20000*64] (2.56 MB — fits per-XCD L2)
#define OFF_V1      7137280u     // fp16[20000*64]
#define OFF_HBUF    12257280u    // u32 [2][2][64][256]  (2 x bf16 h, untagged)
#define OFF_HFLAG   12519424u    // u32 [2][2][8][64]    (rank flags = step tag)
#define OFF_YSEQ    12781568u    // float[64*1024]
#define OFF_PART    13240320u    // float[16][64][768]

__device__ __forceinline__ unsigned short f2b(float f) {
  union { float f; unsigned u; } v; v.f = f;
  unsigned u = v.u;
  return (unsigned short)((u + 0x7FFFu + ((u >> 16) & 1u)) >> 16);
}

union U16h { unsigned short u; _Float16 h; };
__device__ __forceinline__ float h2f(unsigned short u) {
  U16h t; t.u = u; return (float)t.h;
}
__device__ __forceinline__ unsigned short f2h(float f) {
  U16h t; t.h = (_Float16)f; return t.u;
}

__device__ __forceinline__ int idx_at(const int* p, long long i, int mode64) {
  return mode64 ? p[2*i] : p[i];   // little-endian low word
}

__device__ __forceinline__ float dot4(float4 a, float4 b) {
  return a.x * b.x + a.y * b.y + a.z * b.z + a.w * b.w;
}

// ---------------- small utility kernels ----------------
__global__ void zero2_kernel(int* p1, int n1, int* p2, int n2) {
  int i = blockIdx.x * blockDim.x + threadIdx.x;
  if (i < n1) p1[i] = 0;
  int j = i - n1;
  if (j >= 0 && j < n2) p2[j] = 0;
}

// 64-lane parallel i64 detection
__global__ void detect_i64_kernel(const int* e, int* flag) {
  int lane = threadIdx.x;
  int ok = 1;
  for (int i = lane; i < 256; i += 64) ok &= (e[2 * i + 1] == 0);
  ok = __all(ok);
  if (lane == 0 && blockIdx.x == 0) *flag = ok ? 1 : 0;
}

// atomics only on 20000-entry arrays (no few-address hotspots — R6 lesson)
__global__ void hist_kernel(const int* e, const int* batch, int* deg, int* csrc,
                            int* cntb, const int* flag) {
  int i = blockIdx.x * blockDim.x + threadIdx.x;
  int m = *flag;
  if (i < NE) {
    int s = idx_at(e, i, m);
    int d = idx_at(e, (long long)NE + i, m);
    atomicAdd(&csrc[s], 1);
    atomicAdd(&deg[d], 1);
  }
  if (i < NN) atomicAdd(&cntb[idx_at(batch, i, m)], 1);
}

// blocks 0-19: exclusive scan of csrc chunk b; carry by grid-stride sum of
// csrc[0..b*1000) (no atomics). Also dinv. blocks 20+: v0init fp16.
__global__ __launch_bounds__(1024) void combo_kernel(
    const int* __restrict__ csrc, const int* __restrict__ deg,
    int* __restrict__ row_ptr, int* __restrict__ cursor,
    float* __restrict__ dinv, const int* __restrict__ batch,
    const int* __restrict__ flag, unsigned short* __restrict__ v0) {
  const int tid = threadIdx.x, b = blockIdx.x;
  if (b < 20) {
    __shared__ int sA[1024], sB[1024];
    __shared__ int wred[16];
    __shared__ int carry_s;
    int psum = 0;
    for (int i = tid; i < b * 1000; i += 1024) psum += csrc[i];
    for (int off = 1; off < 64; off <<= 1) psum += __shfl_xor(psum, off);
    if ((tid & 63) == 0) wred[tid >> 6] = psum;
    __syncthreads();
    if (tid == 0) {
      int c = 0;
#pragma unroll
      for (int w = 0; w < 16; ++w) c += wred[w];
      carry_s = c;
    }
    int i = b * 1000 + tid;
    int active = (tid < 1000);
    int v = active ? csrc[i] : 0;
    sA[tid] = v;
    __syncthreads();
    int carry = carry_s;
    int* src = sA; int* dst = sB;
    for (int off = 1; off < 1024; off <<= 1) {
      dst[tid] = src[tid] + (tid >= off ? src[tid - off] : 0);
      __syncthreads();
      int* t = src; src = dst; dst = t;
    }
    if (active) {
      int ex = carry + src[tid] - v;
      row_ptr[i] = ex; cursor[i] = ex;
      dinv[i] = rsqrtf((float)(deg[i] + 1));   // +1 self loop
    }
    if (b == 19 && tid == 0) row_ptr[NN] = carry + src[999];
  } else {
    int m = *flag;
    long long j = (long long)(b - 20) * 1024 + tid;
    if (j < (long long)NN * 64) {
      int n = (int)(j >> 6), gb = (int)(j & 63);
      v0[j] = (idx_at(batch, n, m) == gb) ? (unsigned short)0x3C00 : 0;  // fp16 1.0
    }
  }
}

__global__ void fill_kernel(const int* e, const float* dinv, int* cursor,
                            int* colA, float* wgt, const int* flag) {
  int i = blockIdx.x * blockDim.x + threadIdx.x;
  if (i >= NE) return;
  int m = *flag;
  int s = idx_at(e, i, m);
  int d = idx_at(e, (long long)NE + i, m);
  int pos = atomicAdd(&cursor[s], 1);
  colA[pos] = d;
  wgt[pos] = dinv[s] * dinv[d];
}

// one wave per node; 16-edge ILP; V in fp16 (128 B rows — 2x less traffic and
// whole V fits per-XCD L2). Math in f32; round only on the row store.
__global__ __launch_bounds__(256) void hop_kernel(
    const unsigned short* __restrict__ vin, unsigned short* __restrict__ vout,
    const int* __restrict__ row_ptr, const int* __restrict__ colA,
    const float* __restrict__ wgt, const float* __restrict__ dinv,
    const int* __restrict__ batch, const int* __restrict__ flag) {
  int wid = (blockIdx.x * blockDim.x + threadIdx.x) >> 6;
  int lane = threadIdx.x & 63;
  if (wid >= NN) return;
  const int quad = lane >> 4, l15 = lane & 15;
  const int c4 = l15 * 4;
  float di = dinv[wid];
  int e0 = __builtin_amdgcn_readfirstlane(row_ptr[wid]);
  int e1 = __builtin_amdgcn_readfirstlane(row_ptr[wid + 1]);

  float ax, ay, az, aw;
  {
    float w = (quad == 0) ? di * di : 0.0f;
    ushort4 sv = *(const ushort4*)(vin + (size_t)wid * 64 + c4);
    ax = w * h2f(sv.x); ay = w * h2f(sv.y); az = w * h2f(sv.z); aw = w * h2f(sv.w);
  }
  for (int e = e0; e < e1; e += 16) {
    int i0 = e + quad, i1 = i0 + 4, i2 = i0 + 8, i3 = i0 + 12;
    int a0 = (i0 < e1), a1 = (i1 < e1), a2 = (i2 < e1), a3 = (i3 < e1);
    int j0 = a0 ? i0 : e0, j1 = a1 ? i1 : e0, j2 = a2 ? i2 : e0, j3 = a3 ? i3 : e0;
    int cc0 = colA[j0], cc1 = colA[j1], cc2 = colA[j2], cc3 = colA[j3];
    float w0 = a0 ? wgt[j0] : 0.0f, w1 = a1 ? wgt[j1] : 0.0f;
    float w2 = a2 ? wgt[j2] : 0.0f, w3 = a3 ? wgt[j3] : 0.0f;
    ushort4 v0 = *(const ushort4*)(vin + (size_t)cc0 * 64 + c4);
    ushort4 v1 = *(const ushort4*)(vin + (size_t)cc1 * 64 + c4);
    ushort4 v2 = *(const ushort4*)(vin + (size_t)cc2 * 64 + c4);
    ushort4 v3 = *(const ushort4*)(vin + (size_t)cc3 * 64 + c4);
    ax += w0 * h2f(v0.x) + w1 * h2f(v1.x) + w2 * h2f(v2.x) + w3 * h2f(v3.x);
    ay += w0 * h2f(v0.y) + w1 * h2f(v1.y) + w2 * h2f(v2.y) + w3 * h2f(v3.y);
    az += w0 * h2f(v0.z) + w1 * h2f(v1.z) + w2 * h2f(v2.z) + w3 * h2f(v3.z);
    aw += w0 * h2f(v0.w) + w1 * h2f(v1.w) + w2 * h2f(v2.w) + w3 * h2f(v3.w);
  }
  ax += __shfl_xor(ax, 16); ax += __shfl_xor(ax, 32);
  ay += __shfl_xor(ay, 16); ay += __shfl_xor(ay, 32);
  az += __shfl_xor(az, 16); az += __shfl_xor(az, 32);
  aw += __shfl_xor(aw, 16); aw += __shfl_xor(aw, 32);
  if (quad == 0) {
    int b = idx_at(batch, wid, *flag);
    ushort4 r;
    r.x = f2h((1.0f - ALPHA) * ax + ((b == c4 + 0) ? ALPHA : 0.0f));
    r.y = f2h((1.0f - ALPHA) * ay + ((b == c4 + 1) ? ALPHA : 0.0f));
    r.z = f2h((1.0f - ALPHA) * az + ((b == c4 + 2) ? ALPHA : 0.0f));
    r.w = f2h((1.0f - ALPHA) * aw + ((b == c4 + 3) ? ALPHA : 0.0f));
    *(ushort4*)(vout + (size_t)wid * 64 + c4) = r;
  }
}

// pooled partials, standalone (own low-VGPR allocation, high occupancy —
// R9 lesson: do NOT fuse with the 256-VGPR gru), fp16 S reads.
__global__ __launch_bounds__(256) void spmm_kernel(
    const unsigned short* __restrict__ S, const float* __restrict__ x,
    float* __restrict__ partial) {
  __shared__ float red[4][64][17];
  int tid = threadIdx.x;
  int w = tid >> 6, lane = tid & 63;
  int beta = blockIdx.x;
  int ft = beta % 48, cg = beta / 48;
  int ch = cg * 4 + w;
  int f0 = ft * 16;
  int n0 = (ch * NN) >> 6, n1 = ((ch + 1) * NN) >> 6;
  float acc[16];
#pragma unroll
  for (int f = 0; f < 16; ++f) acc[f] = 0.0f;
  for (int n = n0; n < n1; ++n) {
    float sv = h2f(S[n * 64 + lane]);
    const float4* xr = (const float4*)(x + (size_t)n * DF + f0);
    float4 x0 = xr[0], x1 = xr[1], x2 = xr[2], x3 = xr[3];
    acc[0] += sv * x0.x; acc[1] += sv * x0.y; acc[2] += sv * x0.z; acc[3] += sv * x0.w;
    acc[4] += sv * x1.x; acc[5] += sv * x1.y; acc[6] += sv * x1.z; acc[7] += sv * x1.w;
    acc[8] += sv * x2.x; acc[9] += sv * x2.y; acc[10] += sv * x2.z; acc[11] += sv * x2.w;
    acc[12] += sv * x3.x; acc[13] += sv * x3.y; acc[14] += sv * x3.z; acc[15] += sv * x3.w;
  }
#pragma unroll
  for (int f = 0; f < 16; ++f) red[w][lane][f] = acc[f];
  __syncthreads();
#pragma unroll
  for (int ff = 0; ff < 4; ++ff) {
    int f = w * 4 + ff;
    float s = red[0][lane][f] + red[1][lane][f] + red[2][lane][f] + red[3][lane][f];
    partial[((size_t)(cg * 64 + lane)) * DF + f0 + f] = s;
  }
}

// fused seq MLP: 1024 -> 512 -> 256 -> 14, one block per batch row
__global__ __launch_bounds__(256) void mlp_seq_kernel(
    const float* __restrict__ y_seq,
    const float* __restrict__ w0, const float* __restrict__ b0,
    const float* __restrict__ w1, const float* __restrict__ b1,
    const float* __restrict__ w2, const float* __restrict__ b2,
    float* __restrict__ out) {
  __shared__ float a0[1024], h1[512], h2[256];
  const int tid = threadIdx.x, b = blockIdx.x;
  ((float4*)a0)[tid] = ((const float4*)(y_seq + (size_t)b * 1024))[tid];
  __syncthreads();
  {
    int n = tid * 2;
    float acc0 = b0[n], acc1 = b0[n + 1];
    const float4* wa = (const float4*)(w0 + (size_t)n * 1024);
    const float4* wb = wa + 256;
#pragma unroll 4
    for (int k = 0; k < 256; ++k) {
      float4 av = ((float4*)a0)[k];
      acc0 += dot4(av, wa[k]);
      acc1 += dot4(av, wb[k]);
    }
    h1[n] = fmaxf(acc0, 0.0f);
    h1[n + 1] = fmaxf(acc1, 0.0f);
  }
  __syncthreads();
  {
    float acc = b1[tid];
    const float4* wa = (const float4*)(w1 + (size_t)tid * 512);
#pragma unroll 4
    for (int k = 0; k < 128; ++k) acc += dot4(((float4*)h1)[k], wa[k]);
    h2[tid] = fmaxf(acc, 0.0f);
  }
  __syncthreads();
  if (tid < 224) {
    int o = tid >> 4, l = tid & 15;
    const float4* wa = (const float4*)(w2 + (size_t)o * 256);
    float part = 0.0f;
#pragma unroll
    for (int k = l; k < 64; k += 16) part += dot4(((float4*)h2)[k], wa[k]);
    part += __shfl_xor(part, 1); part += __shfl_xor(part, 2);
    part += __shfl_xor(part, 4); part += __shfl_xor(part, 8);
    if (l == 0) out[b * NCLS + o] = part + b2[o];
  }
}

// fused graph MLP: (16-slab reduce + /cnt) -> 768 -> 384 -> 192 -> 14
__global__ __launch_bounds__(256) void mlp_graph_kernel(
    const float* __restrict__ partial, const int* __restrict__ cntb,
    const float* __restrict__ w0, const float* __restrict__ b0,
    const float* __restrict__ w1, const float* __restrict__ b1,
    const float* __restrict__ w2, const float* __restrict__ b2,
    float* __restrict__ out) {
  __shared__ float a0[768], h1[384], h2[192];
  const int tid = threadIdx.x, b = blockIdx.x;
  int cnt = cntb[b]; if (cnt < 1) cnt = 1;
  const float cinv = 1.0f / (float)cnt;
  if (tid < 192) {
    float4 s = {0, 0, 0, 0};
#pragma unroll
    for (int c = 0; c < 16; ++c) {
      float4 p = ((const float4*)(partial + ((size_t)(c * 64 + b)) * DF))[tid];
      s.x += p.x; s.y += p.y; s.z += p.z; s.w += p.w;
    }
    s.x *= cinv; s.y *= cinv; s.z *= cinv; s.w *= cinv;
    ((float4*)a0)[tid] = s;
  }
  __syncthreads();
  if (tid < 192) {
    int n = tid * 2;
    float acc0 = b0[n], acc1 = b0[n + 1];
    const float4* wa = (const float4*)(w0 + (size_t)n * 768);
    const float4* wb = wa + 192;
#pragma unroll 4
    for (int k = 0; k < 192; ++k) {
      float4 av = ((float4*)a0)[k];
      acc0 += dot4(av, wa[k]);
      acc1 += dot4(av, wb[k]);
    }
    h1[n] = fmaxf(acc0, 0.0f);
    h1[n + 1] = fmaxf(acc1, 0.0f);
  }
  __syncthreads();
  if (tid < 192) {
    float acc = b1[tid];
    const float4* wa = (const float4*)(w1 + (size_t)tid * 384);
#pragma unroll 4
    for (int k = 0; k < 96; ++k) acc += dot4(((float4*)h1)[k], wa[k]);
    h2[tid] = fmaxf(acc, 0.0f);
  }
  __syncthreads();
  if (tid < 224) {
    int o = tid >> 4, l = tid & 15;
    const float4* wa = (const float4*)(w2 + (size_t)o * 192);
    float part = 0.0f;
#pragma unroll
    for (int k = l; k < 48; k += 16) part += dot4(((float4*)h2)[k], wa[k]);
    part += __shfl_xor(part, 1); part += __shfl_xor(part, 2);
    part += __shfl_xor(part, 4); part += __shfl_xor(part, 8);
    if (l == 0) atomicAdd(&out[b * NCLS + o], part + b2[o]);
  }
}

// ---------------- GRU recurrent kernel (R3-proven, standalone) --------------
__global__ __launch_bounds__(64, 1) void gru_kernel(
    const float* __restrict__ seq,
    const float* __restrict__ wih_f, const float* __restrict__ whh_f,
    const float* __restrict__ bih_f, const float* __restrict__ bhh_f,
    const float* __restrict__ wih_b, const float* __restrict__ whh_b,
    const float* __restrict__ bih_b, const float* __restrict__ bhh_b,
    unsigned* __restrict__ hbuf, unsigned* __restrict__ hflag,
    float* __restrict__ y_seq) {
  __shared__ unsigned short hl[8 * 648];   // [8 seqs][h(512) | x(128) | pad]

  const int lane = threadIdx.x;           // 0..63
  const int quad = lane >> 4, l15 = lane & 15;
  const int d  = blockIdx.x >> 8;         // 0 fwd, 1 bwd
  const int g  = (blockIdx.x >> 5) & 7;   // 8 groups
  const int rk = blockIdx.x & 31;         // 32 ranks
  const int seqbase = g * 8;
  const int c0 = rk * 16;

  const float* WHHd = d ? whh_b : whh_f;
  const float* WIHd = d ? wih_b : wih_f;
  const float* BIHd = d ? bih_b : bih_f;
  const float* BHHd = d ? bhh_b : bhh_f;

  auto ldw = [&](int gcol, int j) -> short8 {
    int k0 = j * 32 + quad * 8;
    const float* p = (k0 < 512) ? (WHHd + (size_t)gcol * 512 + k0)
                                : (WIHd + (size_t)gcol * 128 + (k0 - 512));
    float4 f0 = *(const float4*)p;
    float4 f1 = *(const float4*)(p + 4);
    short8 r;
    r[0] = (short)f2b(f0.x); r[1] = (short)f2b(f0.y);
    r[2] = (short)f2b(f0.z); r[3] = (short)f2b(f0.w);
    r[4] = (short)f2b(f1.x); r[5] = (short)f2b(f1.y);
    r[6] = (short)f2b(f1.z); r[7] = (short)f2b(f1.w);
    return r;
  };
  short8 wr[20], wz[20], wn[20];
#pragma unroll
  for (int j = 0; j < 20; ++j) {
    wr[j] = ldw(c0 + l15, j);
    wz[j] = ldw(512 + c0 + l15, j);
    wn[j] = ldw(1024 + c0 + l15, j);
  }

  auto stage_x = [&](int t_x) {
    int tt = d ? (127 - t_x) : t_x;
    int s = lane >> 3, k0 = (lane & 7) * 16;
    const float* sp = seq + (size_t)(seqbase + s) * (TSEQ * SF) + tt * SF + k0;
    float4 a = *(const float4*)sp;
    float4 b = *(const float4*)(sp + 4);
    float4 c = *(const float4*)(sp + 8);
    float4 e = *(const float4*)(sp + 12);
    unsigned* xq = (unsigned*)(hl + s * 648 + 512 + k0);   // 16B aligned
    xq[0] = (unsigned)f2b(a.x) | ((unsigned)f2b(a.y) << 16);
    xq[1] = (unsigned)f2b(a.z) | ((unsigned)f2b(a.w) << 16);
    xq[2] = (unsigned)f2b(b.x) | ((unsigned)f2b(b.y) << 16);
    xq[3] = (unsigned)f2b(b.z) | ((unsigned)f2b(b.w) << 16);
    xq[4] = (unsigned)f2b(c.x) | ((unsigned)f2b(c.y) << 16);
    xq[5] = (unsigned)f2b(c.z) | ((unsigned)f2b(c.w) << 16);
    xq[6] = (unsigned)f2b(e.x) | ((unsigned)f2b(e.y) << 16);
    xq[7] = (unsigned)f2b(e.z) | ((unsigned)f2b(e.w) << 16);
  };

  for (int i = lane; i < 8 * 512; i += 64)
    hl[(i >> 9) * 648 + (i & 511)] = 0;
  stage_x(0);

  const float b_r  = BIHd[c0 + l15] + BHHd[c0 + l15];
  const float b_z  = BIHd[512 + c0 + l15] + BHHd[512 + c0 + l15];
  const float b_in = BIHd[1024 + c0 + l15];
  const float b_hn = BHHd[1024 + c0 + l15];

  float hprev[4] = {0, 0, 0, 0};
  float msum[4]  = {0, 0, 0, 0};
  float mxv[4]   = {-1e30f, -1e30f, -1e30f, -1e30f};

  for (int t = 0; t < 128; ++t) {
    f32x4 ar = {0, 0, 0, 0}, az = {0, 0, 0, 0};
    f32x4 anh = {0, 0, 0, 0}, anx = {0, 0, 0, 0};
    const unsigned short* arow = hl + (l15 & 7) * 648 + quad * 8;
#pragma unroll
    for (int kc = 0; kc < 20; ++kc) {
      short8 af = *(const short8*)(arow + kc * 32);
      ar = __builtin_amdgcn_mfma_f32_16x16x32_bf16(af, wr[kc], ar, 0, 0, 0);
      az = __builtin_amdgcn_mfma_f32_16x16x32_bf16(af, wz[kc], az, 0, 0, 0);
      if (kc < 16)
        anh = __builtin_amdgcn_mfma_f32_16x16x32_bf16(af, wn[kc], anh, 0, 0, 0);
      else
        anx = __builtin_amdgcn_mfma_f32_16x16x32_bf16(af, wn[kc], anx, 0, 0, 0);
    }

    float h2v[4];
#pragma unroll
    for (int rr = 0; rr < 4; ++rr) {
      float r = 1.0f / (1.0f + __expf(-(ar[rr] + b_r)));
      float z = 1.0f / (1.0f + __expf(-(az[rr] + b_z)));
      float narg = anx[rr] + b_in + r * (anh[rr] + b_hn);
      float e2 = __expf(-2.0f * fabsf(narg));
      float nt = (1.0f - e2) / (1.0f + e2);
      nt = (narg < 0.0f) ? -nt : nt;
      float h2 = (1.0f - z) * nt + z * hprev[rr];
      hprev[rr] = h2; msum[rr] += h2; mxv[rr] = fmaxf(mxv[rr], h2);
      h2v[rr] = h2;
    }

    if (t < 127) {
      const int slot = (t + 1) & 1;
      const unsigned tag = (unsigned)(t + 1);
#pragma unroll
      for (int rr = 0; rr < 4; ++rr) {
        unsigned me = f2b(h2v[rr]);
        unsigned nb = (unsigned)__shfl_xor((int)me, 1);
        if (lane < 32 && !(lane & 1)) {
          int row = (lane >> 4) * 4 + rr;
          unsigned word = (me & 0xFFFFu) | (nb << 16);
          unsigned* dp = hbuf +
              ((size_t)((slot * 2 + d) * 64 + seqbase + row)) * 256 +
              (unsigned)((c0 + (lane & 15)) >> 1);
          asm volatile("global_store_dword %0, %1, off sc0 sc1"
                       :: "v"(dp), "v"(word) : "memory");
        }
      }
      asm volatile("s_waitcnt vmcnt(0)" ::: "memory");   // release: data ack'd
      if (lane == 0) {
        unsigned* fpo = hflag + ((size_t)(slot * 2 + d) * 8 + g) * 64 + rk;
        unsigned tv = tag;
        asm volatile("global_store_dword %0, %1, off sc0 sc1"
                     :: "v"(fpo), "v"(tv) : "memory");
      }
      stage_x(t + 1);
      const unsigned* fp = hflag + ((size_t)(slot * 2 + d) * 8 + g) * 64 + (lane & 31);
      int guard = 0;
      unsigned fv;
      for (;;) {
        asm volatile("global_load_dword %0, %1, off sc0 sc1"
                     : "=v"(fv) : "v"(fp) : "memory");
        asm volatile("s_waitcnt vmcnt(0)" ::: "memory");
        __builtin_amdgcn_sched_barrier(0);
        if (__all(fv == tag)) break;
        if (++guard > (1 << 20)) break;
        __builtin_amdgcn_s_sleep(1);
      }
      const unsigned* db = hbuf + (size_t)((slot * 2 + d) * 64 + seqbase) * 256;
      u32x4 w[8];
#pragma unroll
      for (int c = 0; c < 8; ++c)
        asm volatile("global_load_dwordx4 %0, %1, off sc0 sc1"
                     : "=v"(w[c]) : "v"(db + c * 256 + lane * 4) : "memory");
      asm volatile("s_waitcnt vmcnt(0)" ::: "memory");
      __builtin_amdgcn_sched_barrier(0);
#pragma unroll
      for (int c = 0; c < 8; ++c) {
        unsigned* dp = (unsigned*)(hl + c * 648) + lane * 4;
        dp[0] = w[c][0]; dp[1] = w[c][1]; dp[2] = w[c][2]; dp[3] = w[c][3];
      }
    }
  }

  if (lane < 32) {
#pragma unroll
    for (int rr = 0; rr < 4; ++rr) {
      int row = (lane >> 4) * 4 + rr;
      y_seq[(size_t)(seqbase + row) * 1024 + d * 512 + c0 + l15] =
          msum[rr] * (1.0f / 128.0f) + mxv[rr];
    }
  }
}

// ---------------- launcher ----------------
extern "C" void kernel_launch(void* const* d_in, const int* in_sizes, int n_in,
                              void* d_out, int out_size, void* d_ws, size_t ws_size,
                              hipStream_t stream) {
  const float* x      = (const float*)d_in[0];
  const int*   eidx   = (const int*)d_in[1];
  const float* seq    = (const float*)d_in[2];
  const int*   batch  = (const int*)d_in[3];
  const float* wih_f  = (const float*)d_in[4];
  const float* whh_f  = (const float*)d_in[5];
  const float* bih_f  = (const float*)d_in[6];
  const float* bhh_f  = (const float*)d_in[7];
  const float* wih_b  = (const float*)d_in[8];
  const float* whh_b  = (const float*)d_in[9];
  const float* bih_b  = (const float*)d_in[10];
  const float* bhh_b  = (const float*)d_in[11];
  const float* mg_w0  = (const float*)d_in[12];
  const float* mg_b0  = (const float*)d_in[13];
  const float* mg_w1  = (const float*)d_in[14];
  const float* mg_b1  = (const float*)d_in[15];
  const float* mg_w2  = (const float*)d_in[16];
  const float* mg_b2  = (const float*)d_in[17];
  const float* ms_w0  = (const float*)d_in[18];
  const float* ms_b0  = (const float*)d_in[19];
  const float* ms_w1  = (const float*)d_in[20];
  const float* ms_b1  = (const float*)d_in[21];
  const float* ms_w2  = (const float*)d_in[22];
  const float* ms_b2  = (const float*)d_in[23];
  float* out = (float*)d_out;
  char* ws = (char*)d_ws;

  int*   deg     = (int*)(ws + OFF_DEG);
  int*   csrc    = (int*)(ws + OFF_CSRC);
  int*   cntb    = (int*)(ws + OFF_CNTB);
  int*   flag    = (int*)(ws + OFF_FLAG64);
  int*   row_ptr = (int*)(ws + OFF_ROWPTR);
  int*   cursor  = (int*)(ws + OFF_CURSOR);
  float* dinv    = (float*)(ws + OFF_DINV);
  int*   colA    = (int*)(ws + OFF_COL);
  float* wgtA    = (float*)(ws + OFF_WGT);
  unsigned short* V0 = (unsigned short*)(ws + OFF_V0);
  unsigned short* V1 = (unsigned short*)(ws + OFF_V1);
  unsigned* hbuf = (unsigned*)(ws + OFF_HBUF);
  unsigned* hflag= (unsigned*)(ws + OFF_HFLAG);
  float* y_seq   = (float*)(ws + OFF_YSEQ);
  float* part    = (float*)(ws + OFF_PART);

  // ---- graph prep ----
  zero2_kernel<<<(ZERO_INTS + 2048 + 255) / 256, 256, 0, stream>>>(
      (int*)ws, (int)ZERO_INTS, (int*)(ws + OFF_HFLAG), 2048);
  detect_i64_kernel<<<1, 64, 0, stream>>>(eidx, flag);
  hist_kernel<<<(NE + 255) / 256, 256, 0, stream>>>(eidx, batch, deg, csrc,
                                                    cntb, flag);
  combo_kernel<<<20 + (NN * 64 + 1023) / 1024, 1024, 0, stream>>>(
      csrc, deg, row_ptr, cursor, dinv, batch, flag, V0);
  fill_kernel<<<(NE + 255) / 256, 256, 0, stream>>>(eidx, dinv, cursor, colA, wgtA, flag);

  // ---- APPNP: 16 hop dispatches (fp16 V, 16-edge ILP) ----
  for (int h = 0; h < 16; ++h) {
    const unsigned short* vin = (h & 1) ? V1 : V0;
    unsigned short* vout = (h & 1) ? V0 : V1;
    hop_kernel<<<(NN * 64 + 255) / 256, 256, 0, stream>>>(vin, vout, row_ptr, colA,
                                                          wgtA, dinv, batch, flag);
  }

  // ---- pooled partials (standalone, high occupancy) ----
  spmm_kernel<<<768, 256, 0, stream>>>(V0, x, part);

  // ---- BiGRU (standalone, 1 wave/block) ----
  gru_kernel<<<512, 64, 0, stream>>>(
      seq, wih_f, whh_f, bih_f, bhh_f, wih_b, whh_b, bih_b, bhh_b, hbuf, hflag, y_seq);

  // ---- fused MLPs: seq writes out, graph accumulates ----
  mlp_seq_kernel<<<64, 256, 0, stream>>>(y_seq, ms_w0, ms_b0, ms_w1, ms_b1,
                                         ms_w2, ms_b2, out);
  mlp_graph_kernel<<<64, 256, 0, stream>>>(part, cntb, mg_w0, mg_b0, mg_w1, mg_b1,
                                           mg_w2, mg_b2, out);
  (void)in_sizes; (void)n_in; (void)out_size; (void)ws_size;
}